// Round 3
// baseline (544.619 us; speedup 1.0000x reference)
//
#include <hip/hip_runtime.h>
#include <hip/hip_bf16.h>

#define N_TOTAL   131072
#define D         512
#define D_ATT     256
#define N_HEAD    4
#define N_CLASSES 53
#define BAG       16
#define M_TILE    64
#define BAGS_PER_BLK (M_TILE / BAG)   // 4
#define THREADS   256
#define N_BLOCKS  (N_TOTAL / M_TILE)  // 2048

typedef __attribute__((ext_vector_type(8))) short bf16x8;
typedef __attribute__((ext_vector_type(4))) float f32x4;

__device__ __forceinline__ unsigned short f2bf(float f) {
    __hip_bfloat16 h = __float2bfloat16(f);
    return *reinterpret_cast<unsigned short*>(&h);
}
// round-half-up bf16 pair pack: 2x v_add_u32 + 1x v_perm_b32
__device__ __forceinline__ unsigned int pack_bf(float a, float b) {
    unsigned int ua = __float_as_uint(a) + 0x8000u;
    unsigned int ub = __float_as_uint(b) + 0x8000u;
    return __builtin_amdgcn_perm(ub, ua, 0x07060302u);
}

// Prep: W1 [512][256] f32 -> W1T bf16 [256][512] ; Wc [512][53] -> WcT f32 [53][512]
__global__ void prep_kernel(const float* __restrict__ W1, const float* __restrict__ Wc,
                            unsigned short* __restrict__ W1T, float* __restrict__ WcT) {
    int tid = blockIdx.x * 256 + threadIdx.x;
    if (tid < D * D_ATT) {
        int k = tid >> 8;
        int n = tid & 255;
        W1T[n * D + k] = f2bf(W1[k * D_ATT + n]);
    } else {
        int t2 = tid - D * D_ATT;
        if (t2 < D * N_CLASSES) {
            int k = t2 / N_CLASSES;
            int c = t2 - k * N_CLASSES;
            WcT[c * D + k] = Wc[k * N_CLASSES + c];
        }
    }
}

#define LDR 516    // ldsR row stride in floats

__global__ void __launch_bounds__(THREADS, 3)
fused_kernel(const float* __restrict__ x,
             const unsigned short* __restrict__ W1T,   // bf16 bits [256][512]
             const float* __restrict__ W2,             // [256][4]
             const float* __restrict__ WcT,            // [53][512]
             const float* __restrict__ bc,             // [53]
             float* __restrict__ out)                  // [8192][53]
{
    __shared__ float ldsSp[4][M_TILE][N_HEAD];        // per-wave s partials, 4 KB
    __shared__ float ldsS[M_TILE * N_HEAD];           // 1 KB
    __shared__ float ldsM[BAGS_PER_BLK * N_HEAD];
    __shared__ float ldsDen[BAGS_PER_BLK * N_HEAD];
    __shared__ float ldsW[M_TILE];
    __shared__ __align__(16) float ldsR[BAGS_PER_BLK][LDR];   // 8.25 KB

    const int tid  = threadIdx.x;
    const int wave = tid >> 6;          // 0..3: col-slice of 64
    const int lane = tid & 63;
    const int quad = lane >> 4;
    const int l16  = lane & 15;
    const int wc2  = wave * 64;
    const int row_base = blockIdx.x * M_TILE;

    // ---- barrier-free K loop: acc(64x64) = X(64x512) @ W1T^T(512x64) ----
    // A-frag: A[m=l16][k=quad*8+j], direct from global x (f32 -> bf16 in regs)
    // B-frag: B[k=quad*8+j][n=l16], direct from global W1T (L2-resident)
    const float*          pA = x + (size_t)row_base * D + (size_t)l16 * D + quad * 8;
    const unsigned short* pB = W1T + (size_t)(wc2 + l16) * D + quad * 8;

    f32x4 acc[4][4] = {};
    {
        float4 ra[4][2], rb[4][2];     // A raw double-buffer
        bf16x8 bfrag[4];

        #define LOADA(ks, dst)                                                          \
            { _Pragma("unroll")                                                         \
              for (int mi = 0; mi < 4; ++mi) {                                          \
                  const float* p = pA + (size_t)mi * 16 * D + (ks) * 32;                \
                  dst[mi][0] = *reinterpret_cast<const float4*>(p);                     \
                  dst[mi][1] = *reinterpret_cast<const float4*>(p + 4);                 \
              } }
        #define LOADB(ks)                                                               \
            { _Pragma("unroll")                                                         \
              for (int ni = 0; ni < 4; ++ni)                                            \
                  bfrag[ni] = *reinterpret_cast<const bf16x8*>(                         \
                      pB + (size_t)ni * 16 * D + (ks) * 32); }
        #define STEP(buf)                                                               \
            { _Pragma("unroll")                                                         \
              for (int mi = 0; mi < 4; ++mi) {                                          \
                  bf16x8 af;                                                            \
                  unsigned int* afp = reinterpret_cast<unsigned int*>(&af);             \
                  afp[0] = pack_bf(buf[mi][0].x, buf[mi][0].y);                         \
                  afp[1] = pack_bf(buf[mi][0].z, buf[mi][0].w);                         \
                  afp[2] = pack_bf(buf[mi][1].x, buf[mi][1].y);                         \
                  afp[3] = pack_bf(buf[mi][1].z, buf[mi][1].w);                         \
                  _Pragma("unroll")                                                     \
                  for (int ni = 0; ni < 4; ++ni)                                        \
                      acc[mi][ni] = __builtin_amdgcn_mfma_f32_16x16x32_bf16(            \
                          af, bfrag[ni], acc[mi][ni], 0, 0, 0);                         \
              } }

        LOADA(0, ra);
        #pragma unroll
        for (int ks = 0; ks < 16; ks += 2) {
            LOADB(ks);
            LOADA(ks + 1, rb);
            STEP(ra);
            LOADB(ks + 1);
            if (ks + 2 < 16) LOADA(ks + 2, ra);
            STEP(rb);
        }
        #undef LOADA
        #undef LOADB
        #undef STEP
    }

    // ---- s partials from acc in registers: sp[row][h] = sum_cols tanh(acc)*W2 ----
    {
        float4 w2r[4];
        #pragma unroll
        for (int ni = 0; ni < 4; ++ni)
            w2r[ni] = *reinterpret_cast<const float4*>(&W2[(wc2 + ni * 16 + l16) * 4]);

        #pragma unroll
        for (int mi = 0; mi < 4; ++mi) {
            float sp[4][4] = {};   // [r][h]
            #pragma unroll
            for (int ni = 0; ni < 4; ++ni) {
                f32x4 v = acc[mi][ni];
                #pragma unroll
                for (int r = 0; r < 4; ++r) {
                    float e = __expf(2.f * v[r]);
                    float t = 1.f - 2.f / (e + 1.f);   // tanh
                    sp[r][0] += t * w2r[ni].x;
                    sp[r][1] += t * w2r[ni].y;
                    sp[r][2] += t * w2r[ni].z;
                    sp[r][3] += t * w2r[ni].w;
                }
            }
            // reduce over the 16 col-lanes (l16) via butterfly
            #pragma unroll
            for (int m = 1; m < 16; m <<= 1)
                #pragma unroll
                for (int r = 0; r < 4; ++r)
                    #pragma unroll
                    for (int h = 0; h < 4; ++h)
                        sp[r][h] += __shfl_xor(sp[r][h], m, 64);
            if (l16 == 0) {
                #pragma unroll
                for (int r = 0; r < 4; ++r) {
                    float4 v4 = {sp[r][0], sp[r][1], sp[r][2], sp[r][3]};
                    *reinterpret_cast<float4*>(&ldsSp[wave][mi * 16 + quad * 4 + r][0]) = v4;
                }
            }
        }
    }
    __syncthreads();

    // ---- combine wave partials: s[row][h] ----
    {
        int row = tid >> 2, h = tid & 3;   // 256 threads
        float s = ldsSp[0][row][h] + ldsSp[1][row][h] + ldsSp[2][row][h] + ldsSp[3][row][h];
        ldsS[row * 4 + h] = s;
    }
    __syncthreads();

    // ---- per-bag per-head softmax stats ----
    if (tid < BAGS_PER_BLK * N_HEAD) {        // 16 threads
        int bag = tid >> 2, head = tid & 3;
        float m = -1e30f;
        for (int i = 0; i < BAG; ++i)
            m = fmaxf(m, ldsS[(bag * BAG + i) * 4 + head]);
        float den = 0.f;
        for (int i = 0; i < BAG; ++i)
            den += __expf(ldsS[(bag * BAG + i) * 4 + head] - m);
        ldsM[tid] = m;
        ldsDen[tid] = 1.f / den;
    }
    __syncthreads();
    if (tid < M_TILE) {                        // 64 threads: w[row]
        int row = tid, bag = row >> 4;
        float w = 0.f;
        #pragma unroll
        for (int h = 0; h < 4; ++h)
            w += __expf(ldsS[row * 4 + h] - ldsM[bag * 4 + h]) * ldsDen[bag * 4 + h];
        ldsW[row] = 0.25f * w;
    }
    __syncthreads();

    // ---- pooling: bag_repr[b][d] = sum_i w * x  (one wave per bag, x from L2) ----
    {
        const int b  = wave;                  // 0..3
        const int dc = lane * 8;              // 0..504
        float4 r0 = {0.f, 0.f, 0.f, 0.f}, r1 = {0.f, 0.f, 0.f, 0.f};
        for (int i = 0; i < BAG; ++i) {
            int row = b * BAG + i;
            float wv = ldsW[row];
            const float4* xp = reinterpret_cast<const float4*>(
                &x[(size_t)(row_base + row) * D + dc]);
            float4 a = xp[0], c = xp[1];
            r0.x += wv * a.x; r0.y += wv * a.y; r0.z += wv * a.z; r0.w += wv * a.w;
            r1.x += wv * c.x; r1.y += wv * c.y; r1.z += wv * c.z; r1.w += wv * c.w;
        }
        *reinterpret_cast<float4*>(&ldsR[b][dc])     = r0;
        *reinterpret_cast<float4*>(&ldsR[b][dc + 4]) = r1;
    }
    __syncthreads();

    // ---- classifier: logits[b][c] = bag_repr[b] . WcT[c] + bc[c] ----
    {
        int c = tid >> 1, half = tid & 1;     // 106 active threads, 2 bags each
        if (c < N_CLASSES) {
            int b0 = half * 2, b1 = half * 2 + 1;
            float a0 = 0.f, a1 = 0.f;
            const float4* r0p = reinterpret_cast<const float4*>(&ldsR[b0][0]);
            const float4* r1p = reinterpret_cast<const float4*>(&ldsR[b1][0]);
            const float4* wp  = reinterpret_cast<const float4*>(&WcT[(size_t)c * D]);
            #pragma unroll 8
            for (int j = 0; j < D / 4; ++j) {
                float4 w = wp[j], q0 = r0p[j], q1 = r1p[j];
                a0 += q0.x * w.x + q0.y * w.y + q0.z * w.z + q0.w * w.w;
                a1 += q1.x * w.x + q1.y * w.y + q1.z * w.z + q1.w * w.w;
            }
            float bias = bc[c];
            size_t ob = (size_t)blockIdx.x * BAGS_PER_BLK;
            out[(ob + b0) * N_CLASSES + c] = a0 + bias;
            out[(ob + b1) * N_CLASSES + c] = a1 + bias;
        }
    }
}

extern "C" void kernel_launch(void* const* d_in, const int* in_sizes, int n_in,
                              void* d_out, int out_size, void* d_ws, size_t ws_size,
                              hipStream_t stream) {
    const float* x  = (const float*)d_in[0];
    const float* W1 = (const float*)d_in[1];
    const float* W2 = (const float*)d_in[2];
    const float* Wc = (const float*)d_in[3];
    const float* bc = (const float*)d_in[4];

    unsigned short* W1T = (unsigned short*)d_ws;
    float*          WcT = (float*)((char*)d_ws + (size_t)D * D_ATT * 2);

    int prep_total = D * D_ATT + D * N_CLASSES;
    prep_kernel<<<dim3((prep_total + 255) / 256), dim3(256), 0, stream>>>(W1, Wc, W1T, WcT);

    fused_kernel<<<dim3(N_BLOCKS), dim3(THREADS), 0, stream>>>(
        x, W1T, W2, WcT, bc, (float*)d_out);
}

// Round 5
// 406.870 us; speedup vs baseline: 1.3386x; 1.3386x over previous
//
#include <hip/hip_runtime.h>
#include <hip/hip_bf16.h>

#define N_TOTAL   131072
#define D         512
#define D_ATT     256
#define N_HEAD    4
#define N_CLASSES 53
#define BAG       16
#define M_TILE    64
#define THREADS   256
#define N_BLOCKS  (N_TOTAL / M_TILE)   // 2048
#define BK        32
#define K_ITERS   (D / BK)             // 16
#define NC_PAD    64

typedef __attribute__((ext_vector_type(8))) short bf16x8;
typedef __attribute__((ext_vector_type(4))) float f32x4;

__device__ __forceinline__ unsigned short f2bf(float f) {
    __hip_bfloat16 h = __float2bfloat16(f);
    return *reinterpret_cast<unsigned short*>(&h);
}
// round-half-up bf16 pair pack: dst lo16 = bf16(a), hi16 = bf16(b)
__device__ __forceinline__ unsigned int pack_bf(float a, float b) {
    unsigned int ua = __float_as_uint(a) + 0x8000u;
    unsigned int ub = __float_as_uint(b) + 0x8000u;
    return __builtin_amdgcn_perm(ub, ua, 0x07060302u);
}

typedef __attribute__((address_space(3))) unsigned char lds_u8;
typedef __attribute__((address_space(1))) const unsigned char g_u8;
__device__ __forceinline__ void gload_lds16(const void* g, void* l) {
    __builtin_amdgcn_global_load_lds((g_u8*)g, (lds_u8*)l, 16, 0, 0);
}

// Prep: W1 [512][256] f32 -> W1T bf16 [256][512]
//       Wc [512][53]  f32 -> WcTb bf16 [64][512], rows 53..63 zero
__global__ void prep_kernel(const float* __restrict__ W1, const float* __restrict__ Wc,
                            unsigned short* __restrict__ W1T, unsigned short* __restrict__ WcTb) {
    int tid = blockIdx.x * 256 + threadIdx.x;
    if (tid < D * D_ATT) {
        int k = tid >> 8;        // 0..511
        int n = tid & 255;       // 0..255
        W1T[n * D + k] = f2bf(W1[k * D_ATT + n]);
    } else {
        int t2 = tid - D * D_ATT;          // 0..32767
        int n = t2 >> 9;                   // 0..63
        int k = t2 & 511;
        WcTb[n * D + k] = (n < N_CLASSES) ? f2bf(Wc[k * N_CLASSES + n])
                                          : (unsigned short)0;
    }
}

// A-fragment: rows r, k = quad*8..+7, from swizzled f32 LDS tile, packed to bf16
__device__ __forceinline__ bf16x8 read_a_frag(const unsigned char* ldsAbase, int r, int quad) {
    const int m = r & 7;
    const float4 u0 = *reinterpret_cast<const float4*>(
        ldsAbase + (size_t)(r * 8 + ((quad * 2)     ^ m)) * 16);
    const float4 u1 = *reinterpret_cast<const float4*>(
        ldsAbase + (size_t)(r * 8 + ((quad * 2 + 1) ^ m)) * 16);
    bf16x8 o;
    unsigned int* op = reinterpret_cast<unsigned int*>(&o);
    op[0] = pack_bf(u0.x, u0.y);
    op[1] = pack_bf(u0.z, u0.w);
    op[2] = pack_bf(u1.x, u1.y);
    op[3] = pack_bf(u1.z, u1.w);
    return o;
}
// B/C-fragment: row n, k = quad*8..+7, bf16 LDS tile (swizzled by (n>>1)&3)
__device__ __forceinline__ bf16x8 read_b_frag(const unsigned char* base, int n, int quad) {
    const int pos = quad ^ ((n >> 1) & 3);
    return *reinterpret_cast<const bf16x8*>(base + (size_t)(n * 4 + pos) * 16);
}

__global__ void __launch_bounds__(THREADS, 3)
fused_kernel(const float* __restrict__ x,
             const unsigned short* __restrict__ W1T,    // bf16 [256][512]
             const unsigned short* __restrict__ WcTb,   // bf16 [64][512]
             const float* __restrict__ W2,              // f32 [256][4]
             const float* __restrict__ bc,              // f32 [53]
             float* __restrict__ out)                   // f32 [8192][53]
{
    __shared__ __align__(16) unsigned char ldsA[M_TILE * BK * 4];   // 8 KB  (f32, swizzled)
    __shared__ __align__(16) unsigned char ldsB[D_ATT * BK * 2];    // 16 KB (bf16, swizzled)
    __shared__ __align__(16) unsigned char ldsC[NC_PAD * BK * 2];   // 4 KB  (bf16, swizzled)
    __shared__ float ldsSp[4][M_TILE][N_HEAD];                      // 4 KB
    __shared__ float ldsS[M_TILE][N_HEAD];
    __shared__ float ldsM[4][N_HEAD];
    __shared__ float ldsDen[4][N_HEAD];
    __shared__ float ldsW[M_TILE];

    const int tid  = threadIdx.x;
    const int wave = tid >> 6;          // 0..3 = bag index within block
    const int lane = tid & 63;
    const int quad = lane >> 4;
    const int l16  = lane & 15;
    const int row_base = blockIdx.x * M_TILE;

    // ---- staging source addresses (global side carries the swizzle) ----
    // A: 512 chunks of 16 B; chunk c: r=c>>3, p=c&7 stores col-group j=p^(r&7)
    // B: 1024 chunks;        chunk c: n=c>>2, p=c&3 stores col-group j=p^((n>>1)&3)
    // C: 256 chunks;         same mapping as B
    const char* gA[2]; unsigned lA[2];
    #pragma unroll
    for (int i = 0; i < 2; ++i) {
        int c = tid + 256 * i, r = c >> 3, p = c & 7, j = p ^ (r & 7);
        gA[i] = (const char*)(x + (size_t)(row_base + r) * D + j * 4);
        lA[i] = c * 16;
    }
    const char* gB[4]; unsigned lB[4];
    #pragma unroll
    for (int i = 0; i < 4; ++i) {
        int c = tid + 256 * i, n = c >> 2, p = c & 3, j = p ^ ((n >> 1) & 3);
        gB[i] = (const char*)(W1T + (size_t)n * D + j * 8);
        lB[i] = c * 16;
    }
    const char* gC; unsigned lC;
    {
        int c = tid, n = c >> 2, p = c & 3, j = p ^ ((n >> 1) & 3);
        gC = (const char*)(WcTb + (size_t)n * D + j * 8);
        lC = c * 16;
    }

    f32x4 acc[4][4] = {};    // s-GEMM: 64 rows x 64 cols per wave (col slice wave*64)
    f32x4 accY[4]   = {};    // y-GEMM: this wave's 16 rows x 64 cols

    // ---- m97-pattern K loop: single buffer, two barriers ----
    for (int kt = 0; kt < K_ITERS; ++kt) {
        const size_t ao = (size_t)kt * (BK * 4);   // 128 B per tile step
        const size_t bo = (size_t)kt * (BK * 2);   // 64 B
        gload_lds16(gA[0] + ao, ldsA + lA[0]);
        gload_lds16(gA[1] + ao, ldsA + lA[1]);
        gload_lds16(gB[0] + bo, ldsB + lB[0]);
        gload_lds16(gB[1] + bo, ldsB + lB[1]);
        gload_lds16(gB[2] + bo, ldsB + lB[2]);
        gload_lds16(gB[3] + bo, ldsB + lB[3]);
        gload_lds16(gC + bo,    ldsC + lC);
        __syncthreads();   // compiler drains vmcnt before barrier -> tile resident

        bf16x8 afr[4];
        #pragma unroll
        for (int mi = 0; mi < 4; ++mi)
            afr[mi] = read_a_frag(ldsA, mi * 16 + l16, quad);
        bf16x8 bfr[4];
        #pragma unroll
        for (int ni = 0; ni < 4; ++ni)
            bfr[ni] = read_b_frag(ldsB, wave * 64 + ni * 16 + l16, quad);
        #pragma unroll
        for (int mi = 0; mi < 4; ++mi)
            #pragma unroll
            for (int ni = 0; ni < 4; ++ni)
                acc[mi][ni] = __builtin_amdgcn_mfma_f32_16x16x32_bf16(
                    afr[mi], bfr[ni], acc[mi][ni], 0, 0, 0);

        // y-GEMM: A rows of this wave's bag, B = Wc columns
        bf16x8 ay = read_a_frag(ldsA, wave * 16 + l16, quad);
        #pragma unroll
        for (int ni = 0; ni < 4; ++ni) {
            bf16x8 cf = read_b_frag(ldsC, ni * 16 + l16, quad);
            accY[ni] = __builtin_amdgcn_mfma_f32_16x16x32_bf16(
                ay, cf, accY[ni], 0, 0, 0);
        }
        __syncthreads();   // protect single buffer before next issue
    }

    // ---- s partials: tanh + W2, butterfly over 16 col-lanes ----
    {
        float4 w2r[4];
        #pragma unroll
        for (int ni = 0; ni < 4; ++ni)
            w2r[ni] = *reinterpret_cast<const float4*>(&W2[(wave * 64 + ni * 16 + l16) * 4]);

        #pragma unroll
        for (int mi = 0; mi < 4; ++mi) {
            float sp[4][4] = {};   // [r][h]
            #pragma unroll
            for (int ni = 0; ni < 4; ++ni) {
                f32x4 v = acc[mi][ni];
                #pragma unroll
                for (int r = 0; r < 4; ++r) {
                    float e = __expf(2.f * v[r]);
                    float t = 1.f - 2.f / (e + 1.f);   // tanh
                    sp[r][0] += t * w2r[ni].x;
                    sp[r][1] += t * w2r[ni].y;
                    sp[r][2] += t * w2r[ni].z;
                    sp[r][3] += t * w2r[ni].w;
                }
            }
            #pragma unroll
            for (int msk = 1; msk < 16; msk <<= 1)
                #pragma unroll
                for (int r = 0; r < 4; ++r)
                    #pragma unroll
                    for (int h = 0; h < 4; ++h)
                        sp[r][h] += __shfl_xor(sp[r][h], msk, 64);
            if (l16 == 0) {
                #pragma unroll
                for (int r = 0; r < 4; ++r) {
                    int row = mi * 16 + quad * 4 + r;
                    float4 v4 = {sp[r][0], sp[r][1], sp[r][2], sp[r][3]};
                    *reinterpret_cast<float4*>(&ldsSp[wave][row][0]) = v4;
                }
            }
        }
    }
    __syncthreads();

    // ---- combine wave partials ----
    {
        int row = tid >> 2, h = tid & 3;   // 256 threads = 64 rows x 4 heads
        ldsS[row][h] = ldsSp[0][row][h] + ldsSp[1][row][h]
                     + ldsSp[2][row][h] + ldsSp[3][row][h];
    }
    __syncthreads();

    // ---- per-bag per-head softmax stats ----
    if (tid < 4 * N_HEAD) {                 // 16 threads
        int bag = tid >> 2, head = tid & 3;
        float m = -1e30f;
        for (int i = 0; i < BAG; ++i)
            m = fmaxf(m, ldsS[bag * BAG + i][head]);
        float den = 0.f;
        for (int i = 0; i < BAG; ++i)
            den += __expf(ldsS[bag * BAG + i][head] - m);
        ldsM[bag][head] = m;
        ldsDen[bag][head] = 1.f / den;
    }
    __syncthreads();
    if (tid < M_TILE) {                      // 64 threads: w[row]
        int row = tid, bag = row >> 4;
        float w = 0.f;
        #pragma unroll
        for (int h = 0; h < 4; ++h)
            w += __expf(ldsS[row][h] - ldsM[bag][h]) * ldsDen[bag][h];
        ldsW[row] = 0.25f * w;
    }
    __syncthreads();

    // ---- logits from accY (wave == bag): weighted row-sum + quad reduction ----
    {
        float p[4];
        #pragma unroll
        for (int ni = 0; ni < 4; ++ni) {
            f32x4 v = accY[ni];
            float s = 0.f;
            #pragma unroll
            for (int r = 0; r < 4; ++r)
                s += ldsW[wave * 16 + quad * 4 + r] * v[r];
            s += __shfl_xor(s, 16, 64);
            s += __shfl_xor(s, 32, 64);
            p[ni] = s;
        }
        if (quad == 0) {
            size_t bag = (size_t)blockIdx.x * 4 + wave;
            #pragma unroll
            for (int ni = 0; ni < 4; ++ni) {
                int c = ni * 16 + l16;
                if (c < N_CLASSES)
                    out[bag * N_CLASSES + c] = p[ni] + bc[c];
            }
        }
    }
}

extern "C" void kernel_launch(void* const* d_in, const int* in_sizes, int n_in,
                              void* d_out, int out_size, void* d_ws, size_t ws_size,
                              hipStream_t stream) {
    const float* x  = (const float*)d_in[0];
    const float* W1 = (const float*)d_in[1];
    const float* W2 = (const float*)d_in[2];
    const float* Wc = (const float*)d_in[3];
    const float* bc = (const float*)d_in[4];

    unsigned short* W1T  = (unsigned short*)d_ws;                          // 262144 B
    unsigned short* WcTb = (unsigned short*)((char*)d_ws + 262144);        // 65536 B

    prep_kernel<<<dim3(640), dim3(256), 0, stream>>>(W1, Wc, W1T, WcTb);

    fused_kernel<<<dim3(N_BLOCKS), dim3(THREADS), 0, stream>>>(
        x, W1T, WcTb, W2, bc, (float*)d_out);
}